// Round 3
// baseline (71.193 us; speedup 1.0000x reference)
//
#include <hip/hip_runtime.h>
#include <hip/hip_bf16.h>

#define BB 16
#define TT 2048
#define HH 1024
#define NTAGS 74
#define NPAD 80
#define KSPLIT 4
#define KCH (HH / KSPLIT)  // 256 per wave

typedef __bf16 bf16x8 __attribute__((ext_vector_type(8)));
typedef float f32x4 __attribute__((ext_vector_type(4)));

// Transpose + convert W_out [1024][74] f32 -> Wt [80][1024] bf16 (pad cols 74..79 = 0)
__global__ __launch_bounds__(256) void prep_w_kernel(const float* __restrict__ W,
                                                     __bf16* __restrict__ Wt) {
    __shared__ float tile[64][80];
    const int k0 = blockIdx.x * 64;
    const int tid = threadIdx.x;
    for (int i = tid; i < 64 * NTAGS; i += 256) {
        int k = i / NTAGS, n = i - k * NTAGS;
        tile[k][n] = W[(k0 + k) * NTAGS + n];
    }
    __syncthreads();
    for (int i = tid; i < NPAD * 64; i += 256) {
        int n = i >> 6, kk = i & 63;
        float v = (n < NTAGS) ? tile[kk][n] : 0.0f;
        Wt[n * HH + k0 + kk] = (__bf16)v;
    }
}

// Fused gather-blend-mask + GEMM [B*T,1024]x[1024,74], 16x16x32 bf16 MFMA.
// Split-K x4: block = 4 waves, all on the SAME 16 rows; wave w owns K-quarter
// [w*256, (w+1)*256). Partials reduced via LDS; bias added once.
// A-fragments built straight from global: lane l -> row (l&15), k contiguous
// per (l>>4); any k-permutation cancels (A and B share the mapping).
__global__ __launch_bounds__(256, 8) void slu_main(const float* __restrict__ out_char,
                                                   const float* __restrict__ out_word,
                                                   const int* __restrict__ word_idx,
                                                   const int* __restrict__ is_head,
                                                   const int* __restrict__ valid_mask,
                                                   const __bf16* __restrict__ Wt,
                                                   const float* __restrict__ b_out,
                                                   float* __restrict__ out) {
    const int tid = threadIdx.x;
    const int wv = tid >> 6;      // wave 0..3 = K-quarter index
    const int lane = tid & 63;
    const int l15 = lane & 15;
    const int kgrp = lane >> 4;   // 0..3

    const int row = blockIdx.x * 16 + l15;  // this lane's A row (== b*T+t)
    const int b = row >> 11;                // T = 2048
    const int bt = row;

    const int widx = word_idx[bt];
    const bool val = valid_mask[bt] != 0;
    const bool head = is_head[bt] != 0;
    const float r = head ? 0.88f : 0.70f;
    const float rate = val ? r : 0.0f;
    const float crate = val ? (1.0f - r) : 0.0f;

    const int kbase = wv * KCH;
    const float* cp = out_char + (size_t)bt * HH + kbase + kgrp * 8;
    const float* wp = out_word + ((size_t)b * TT + widx) * HH + kbase + kgrp * 8;
    const __bf16* wtp = Wt + l15 * HH + kbase + kgrp * 8;

    f32x4 acc[5];
#pragma unroll
    for (int nt = 0; nt < 5; ++nt) acc[nt] = (f32x4){0.0f, 0.0f, 0.0f, 0.0f};

#pragma unroll
    for (int k0 = 0; k0 < KCH; k0 += 32) {
        bf16x8 a;
        if (val) {
            float4 ca = *(const float4*)(cp + k0);
            float4 cb = *(const float4*)(cp + k0 + 4);
            float4 wa = *(const float4*)(wp + k0);
            float4 wb = *(const float4*)(wp + k0 + 4);
            a[0] = (__bf16)(wa.x * rate + ca.x * crate);
            a[1] = (__bf16)(wa.y * rate + ca.y * crate);
            a[2] = (__bf16)(wa.z * rate + ca.z * crate);
            a[3] = (__bf16)(wa.w * rate + ca.w * crate);
            a[4] = (__bf16)(wb.x * rate + cb.x * crate);
            a[5] = (__bf16)(wb.y * rate + cb.y * crate);
            a[6] = (__bf16)(wb.z * rate + cb.z * crate);
            a[7] = (__bf16)(wb.w * rate + cb.w * crate);
        } else {
#pragma unroll
            for (int e = 0; e < 8; ++e) a[e] = (__bf16)0.0f;
        }
#pragma unroll
        for (int nt = 0; nt < 5; ++nt) {
            bf16x8 bf = *(const bf16x8*)(wtp + nt * 16 * HH + k0);
            acc[nt] = __builtin_amdgcn_mfma_f32_16x16x32_bf16(a, bf, acc[nt], 0, 0, 0);
        }
    }

    // Cross-wave split-K reduction through LDS (20 KB).
    __shared__ f32x4 part[KSPLIT][5][64];
#pragma unroll
    for (int nt = 0; nt < 5; ++nt) part[wv][nt][lane] = acc[nt];
    __syncthreads();

    // C/D layout: col = lane&15, row = (lane>>4)*4 + reg   [m89-verified]
    const int orow = blockIdx.x * 16 + kgrp * 4;
    for (int nt = wv; nt < 5; nt += KSPLIT) {
        f32x4 s = part[0][nt][lane];
#pragma unroll
        for (int w = 1; w < KSPLIT; ++w) s += part[w][nt][lane];
        const int col = nt * 16 + l15;
        if (col < NTAGS) {
            const float bias = b_out[col];
#pragma unroll
            for (int i = 0; i < 4; ++i) {
                out[(size_t)(orow + i) * NTAGS + col] = s[i] + bias;
            }
        }
    }
}

extern "C" void kernel_launch(void* const* d_in, const int* in_sizes, int n_in,
                              void* d_out, int out_size, void* d_ws, size_t ws_size,
                              hipStream_t stream) {
    const float* out_char = (const float*)d_in[0];
    const float* out_word = (const float*)d_in[1];
    const int* word_idx = (const int*)d_in[2];
    const int* is_head = (const int*)d_in[3];
    const int* valid_mask = (const int*)d_in[4];
    const float* W_out = (const float*)d_in[5];
    const float* b_out = (const float*)d_in[6];
    float* out = (float*)d_out;
    __bf16* Wt = (__bf16*)d_ws;  // 80*1024*2 = 160 KB

    prep_w_kernel<<<HH / 64, 256, 0, stream>>>(W_out, Wt);

    const int rows = BB * TT;
    slu_main<<<rows / 16, 256, 0, stream>>>(out_char, out_word, word_idx, is_head,
                                            valid_mask, Wt, b_out, out);
}

// Round 4
// 48.446 us; speedup vs baseline: 1.4695x; 1.4695x over previous
//
#include <hip/hip_runtime.h>
#include <hip/hip_bf16.h>

#define TT 2048
#define HH 1024
#define NTAGS 74
#define NPAD 80
#define CHK 128           // K elements per chunk
#define NCH (HH / CHK)    // 8 chunks

typedef __bf16 bf16x8 __attribute__((ext_vector_type(8)));
typedef __bf16 bf16x4 __attribute__((ext_vector_type(4)));
typedef float f32x4 __attribute__((ext_vector_type(4)));

// Transpose + convert W_out [1024][74] f32 -> Wt [80][1024] bf16 (pad cols 74..79 = 0)
__global__ __launch_bounds__(256) void prep_w_kernel(const float* __restrict__ W,
                                                     __bf16* __restrict__ Wt) {
    __shared__ float tile[64][80];
    const int k0 = blockIdx.x * 64;
    const int tid = threadIdx.x;
    for (int i = tid; i < 64 * NTAGS; i += 256) {
        int k = i / NTAGS, n = i - k * NTAGS;
        tile[k][n] = W[(k0 + k) * NTAGS + n];
    }
    __syncthreads();
    for (int i = tid; i < NPAD * 64; i += 256) {
        int n = i >> 6, kk = i & 63;
        float v = (n < NTAGS) ? tile[kk][n] : 0.0f;
        Wt[n * HH + k0 + kk] = (__bf16)v;
    }
}

// Fused gather-blend + GEMM, LDS-staged with fully-coalesced global loads.
// Block = 256 thr (4 waves) x 16 rows x full K (8 chunks of 128).
// Per chunk: stage A (blend char/word -> bf16) and Wt chunk into swizzled,
// double-buffered LDS; wave w computes k-slice w*32 of the chunk (split-K x4).
// LDS map (bytes): A[2] @ 0 (2*4096), W[2] @ 8192 (2*20480) = 49152 total.
// Reduction partials (20 KB) reuse offset 0 after the loop.
__global__ __launch_bounds__(256, 4) void slu_main(const float* __restrict__ out_char,
                                                   const float* __restrict__ out_word,
                                                   const int* __restrict__ word_idx,
                                                   const int* __restrict__ is_head,
                                                   const int* __restrict__ valid_mask,
                                                   const __bf16* __restrict__ Wt,
                                                   const float* __restrict__ b_out,
                                                   float* __restrict__ out) {
    __shared__ __align__(16) char smem[49152];
    const int tid = threadIdx.x;
    const int wv = tid >> 6;
    const int lane = tid & 63;
    const int l15 = lane & 15;
    const int kgrp = lane >> 4;
    const int rowbase = blockIdx.x * 16;

    // ---- staging descriptors ----
    // A: 2 passes, u = tid + 256*p: local row = u>>5 (0..15), 16B-unit = u&31
    const float* acp[2];
    const float* awp[2];
    float arate[2], acrate[2];
    int avalid[2], aoff[2];
#pragma unroll
    for (int p = 0; p < 2; ++p) {
        const int u = tid + 256 * p;
        const int rloc = u >> 5;
        const int unit = u & 31;
        const int r = rowbase + rloc;
        const int b = r >> 11;  // T = 2048
        const int widx = word_idx[r];
        const int val = valid_mask[r];
        const float rt = is_head[r] ? 0.88f : 0.70f;
        arate[p] = val ? rt : 0.0f;
        acrate[p] = val ? (1.0f - rt) : 0.0f;
        avalid[p] = val;
        acp[p] = out_char + (size_t)r * HH + unit * 4;
        awp[p] = out_word + ((size_t)b * TT + widx) * HH + unit * 4;
        aoff[p] = (rloc * 256 + unit * 8) ^ ((rloc & 7) << 4);
    }
    // W: 5 passes, u = tid + 256*p: row n = u>>4 (0..79), 16B-unit = u&15
    const __bf16* wsrc[5];
    int woff[5];
#pragma unroll
    for (int p = 0; p < 5; ++p) {
        const int u = tid + 256 * p;
        const int n = u >> 4, unit = u & 15;
        wsrc[p] = Wt + (size_t)n * HH + unit * 8;
        woff[p] = (n * 256 + unit * 16) ^ ((n & 7) << 4);
    }

    // ---- fragment read offsets (swizzle matches writes) ----
    const int afrag_off = (l15 * 256 + wv * 64 + kgrp * 16) ^ ((l15 & 7) << 4);
    int wfrag_off[5];
#pragma unroll
    for (int nt = 0; nt < 5; ++nt) {
        const int n = nt * 16 + l15;
        wfrag_off[nt] = (n * 256 + wv * 64 + kgrp * 16) ^ ((n & 7) << 4);
    }

    f32x4 acc[5];
#pragma unroll
    for (int nt = 0; nt < 5; ++nt) acc[nt] = (f32x4){0.f, 0.f, 0.f, 0.f};

    // ---- prologue: stage chunk 0 into buffer 0 ----
    {
        float4 c0[2], w0[2];
        bf16x8 wr[5];
#pragma unroll
        for (int p = 0; p < 2; ++p) {
            if (avalid[p]) {
                c0[p] = *(const float4*)(acp[p]);
                w0[p] = *(const float4*)(awp[p]);
            }
        }
#pragma unroll
        for (int p = 0; p < 5; ++p) wr[p] = *(const bf16x8*)(wsrc[p]);
#pragma unroll
        for (int p = 0; p < 2; ++p) {
            bf16x4 fb;
            if (avalid[p]) {
                fb[0] = (__bf16)(w0[p].x * arate[p] + c0[p].x * acrate[p]);
                fb[1] = (__bf16)(w0[p].y * arate[p] + c0[p].y * acrate[p]);
                fb[2] = (__bf16)(w0[p].z * arate[p] + c0[p].z * acrate[p]);
                fb[3] = (__bf16)(w0[p].w * arate[p] + c0[p].w * acrate[p]);
            } else {
                fb[0] = fb[1] = fb[2] = fb[3] = (__bf16)0.0f;
            }
            *(bf16x4*)(smem + aoff[p]) = fb;
        }
#pragma unroll
        for (int p = 0; p < 5; ++p) *(bf16x8*)(smem + 8192 + woff[p]) = wr[p];
    }
    __syncthreads();

    // ---- main loop: issue loads(t+1) -> compute(t) -> blend+write(t+1) -> barrier ----
    for (int ch = 0; ch < NCH; ++ch) {
        const int cur = ch & 1;
        const bool more = (ch + 1 < NCH);
        float4 c1[2], w1[2];
        bf16x8 wr[5];
        if (more) {
            const int koff = (ch + 1) * CHK;
#pragma unroll
            for (int p = 0; p < 2; ++p) {
                if (avalid[p]) {
                    c1[p] = *(const float4*)(acp[p] + koff);
                    w1[p] = *(const float4*)(awp[p] + koff);
                }
            }
#pragma unroll
            for (int p = 0; p < 5; ++p) wr[p] = *(const bf16x8*)(wsrc[p] + koff);
        }

        // compute chunk ch from buf[cur]
        const char* Ab = smem + cur * 4096;
        const char* Wb = smem + 8192 + cur * 20480;
        bf16x8 a = *(const bf16x8*)(Ab + afrag_off);
#pragma unroll
        for (int nt = 0; nt < 5; ++nt) {
            bf16x8 bw = *(const bf16x8*)(Wb + wfrag_off[nt]);
            acc[nt] = __builtin_amdgcn_mfma_f32_16x16x32_bf16(a, bw, acc[nt], 0, 0, 0);
        }

        if (more) {
            char* An = smem + (cur ^ 1) * 4096;
            char* Wn = smem + 8192 + (cur ^ 1) * 20480;
#pragma unroll
            for (int p = 0; p < 2; ++p) {
                bf16x4 fb;
                if (avalid[p]) {
                    fb[0] = (__bf16)(w1[p].x * arate[p] + c1[p].x * acrate[p]);
                    fb[1] = (__bf16)(w1[p].y * arate[p] + c1[p].y * acrate[p]);
                    fb[2] = (__bf16)(w1[p].z * arate[p] + c1[p].z * acrate[p]);
                    fb[3] = (__bf16)(w1[p].w * arate[p] + c1[p].w * acrate[p]);
                } else {
                    fb[0] = fb[1] = fb[2] = fb[3] = (__bf16)0.0f;
                }
                *(bf16x4*)(An + aoff[p]) = fb;
            }
#pragma unroll
            for (int p = 0; p < 5; ++p) *(bf16x8*)(Wn + woff[p]) = wr[p];
        }
        __syncthreads();
    }

    // ---- split-K reduction via LDS (reuses smem; loop's final barrier precedes) ----
    f32x4* part = (f32x4*)smem;  // [4][5][64] = 20 KB
#pragma unroll
    for (int nt = 0; nt < 5; ++nt) part[(wv * 5 + nt) * 64 + lane] = acc[nt];
    __syncthreads();

    // C/D layout: col = lane&15, row = (lane>>4)*4 + reg   [verified R2/R3]
    const int orow = rowbase + kgrp * 4;
    for (int nt = wv; nt < 5; nt += 4) {
        f32x4 s = part[(0 * 5 + nt) * 64 + lane];
#pragma unroll
        for (int w = 1; w < 4; ++w) s += part[(w * 5 + nt) * 64 + lane];
        const int col = nt * 16 + l15;
        if (col < NTAGS) {
            const float bias = b_out[col];
#pragma unroll
            for (int i = 0; i < 4; ++i) {
                out[(size_t)(orow + i) * NTAGS + col] = s[i] + bias;
            }
        }
    }
}

extern "C" void kernel_launch(void* const* d_in, const int* in_sizes, int n_in,
                              void* d_out, int out_size, void* d_ws, size_t ws_size,
                              hipStream_t stream) {
    const float* out_char = (const float*)d_in[0];
    const float* out_word = (const float*)d_in[1];
    const int* word_idx = (const int*)d_in[2];
    const int* is_head = (const int*)d_in[3];
    const int* valid_mask = (const int*)d_in[4];
    const float* W_out = (const float*)d_in[5];
    const float* b_out = (const float*)d_in[6];
    float* out = (float*)d_out;
    __bf16* Wt = (__bf16*)d_ws;  // 80*1024*2 = 160 KB

    prep_w_kernel<<<HH / 64, 256, 0, stream>>>(W_out, Wt);

    const int rows = 16 * TT;  // B*T = 32768
    slu_main<<<rows / 16, 256, 0, stream>>>(out_char, out_word, word_idx, is_head,
                                            valid_mask, Wt, b_out, out);
}

// Round 5
// 35.522 us; speedup vs baseline: 2.0042x; 1.3638x over previous
//
#include <hip/hip_runtime.h>
#include <hip/hip_bf16.h>

#define TT 2048
#define HH 1024
#define NTAGS 74
#define NPAD 80
#define CHK 64            // K elements per chunk
#define NCH (HH / CHK)    // 16 chunks
#define MROWS 64          // rows per block

typedef __bf16 bf16x8 __attribute__((ext_vector_type(8)));
typedef float f32x4 __attribute__((ext_vector_type(4)));

// Transpose + convert W_out [1024][74] f32 -> Wt [80][1024] bf16 (pad cols 74..79 = 0)
__global__ __launch_bounds__(256) void prep_w_kernel(const float* __restrict__ W,
                                                     __bf16* __restrict__ Wt) {
    __shared__ float tile[64][80];
    const int k0 = blockIdx.x * 64;
    const int tid = threadIdx.x;
    for (int i = tid; i < 64 * NTAGS; i += 256) {
        int k = i / NTAGS, n = i - k * NTAGS;
        tile[k][n] = W[(k0 + k) * NTAGS + n];
    }
    __syncthreads();
    for (int i = tid; i < NPAD * 64; i += 256) {
        int n = i >> 6, kk = i & 63;
        float v = (n < NTAGS) ? tile[kk][n] : 0.0f;
        Wt[n * HH + k0 + kk] = (__bf16)v;
    }
}

// Fused gather-blend + skinny GEMM [B*T,1024]x[1024,74] via 16x16x32 bf16 MFMA.
// Block = 256 thr (4 waves), M=64 rows, full K per wave (16 rows each, no split-K).
// K chunks of 64; A triple-buffered (3x8KB), W double-buffered (2x10KB) in LDS,
// XOR-swizzled (byte ^= (row&7)<<4). Pipeline: write(ch+1 from regs) ->
// issue loads(ch+2) -> compute(ch) -> barrier. W traffic amortized 4x vs M=16.
__global__ __launch_bounds__(256, 2) void slu_main(const float* __restrict__ out_char,
                                                   const float* __restrict__ out_word,
                                                   const int* __restrict__ word_idx,
                                                   const int* __restrict__ is_head,
                                                   const int* __restrict__ valid_mask,
                                                   const __bf16* __restrict__ Wt,
                                                   const float* __restrict__ b_out,
                                                   float* __restrict__ out) {
    // LDS: A[3] @ 0 (3*8192), W[2] @ 24576 (2*10240) = 45056 B
    __shared__ __align__(16) char smem[45056];
    const int tid = threadIdx.x;
    const int wv = tid >> 6;
    const int lane = tid & 63;
    const int l15 = lane & 15;
    const int kgrp = lane >> 4;
    const int rowbase = blockIdx.x * MROWS;

    // ---- A staging descriptors: thread covers row rloc=(tid>>2), k-sub q=(tid&3) (16 f32) ----
    const int rloc = tid >> 2;
    const int q = tid & 3;
    const int r = rowbase + rloc;
    const int bq = r >> 11;  // T = 2048
    const int widx = word_idx[r];
    const int val = valid_mask[r];
    const float rt = is_head[r] ? 0.88f : 0.70f;
    const float rate = val ? rt : 0.0f;
    const float crate = val ? (1.0f - rt) : 0.0f;
    const float* cptr = out_char + (size_t)r * HH + q * 16;
    const float* wptr = out_word + ((size_t)bq * TT + widx) * HH + q * 16;
    const int asw = (rloc & 7) << 4;
    const int awr0 = (rloc * 128 + q * 32) ^ asw;
    const int awr1 = (rloc * 128 + q * 32 + 16) ^ asw;

    // ---- W staging: 640 16B-units/chunk; thread covers units tid, tid+256, (tid<128)?tid+512 ----
    const int wn0 = tid >> 3, wsb = tid & 7;
    const __bf16* wgp0 = Wt + (size_t)wn0 * HH + wsb * 8;
    const __bf16* wgp1 = wgp0 + 32 * HH;
    const __bf16* wgp2 = wgp0 + 64 * HH;
    const int wsw = (wn0 & 7) << 4;
    const int wwr0 = (wn0 * 128 + wsb * 16) ^ wsw;
    const int wwr1 = ((wn0 + 32) * 128 + wsb * 16) ^ wsw;
    const int wwr2 = ((wn0 + 64) * 128 + wsb * 16) ^ wsw;
    const bool w3 = (tid < 128);

    // ---- fragment read offsets (swizzle matches writes; row&7 == l15&7 both A and W) ----
    const int fsw = (l15 & 7) << 4;
    const int arow = wv * 16 + l15;
    int aoff[2], woff[2][5];
#pragma unroll
    for (int s = 0; s < 2; ++s) {
        aoff[s] = (arow * 128 + s * 64 + kgrp * 16) ^ fsw;
#pragma unroll
        for (int nt = 0; nt < 5; ++nt)
            woff[s][nt] = ((nt * 16 + l15) * 128 + s * 64 + kgrp * 16) ^ fsw;
    }

    f32x4 acc[5];
#pragma unroll
    for (int nt = 0; nt < 5; ++nt) acc[nt] = (f32x4){0.f, 0.f, 0.f, 0.f};

    float4 ac[4], aw[4];   // held A loads (next-next chunk)
    bf16x8 wreg0, wreg1, wreg2;

    // ---- prologue: stage chunk 0 directly; prefetch chunk 1 into regs ----
    {
        float4 c0[4], w0[4];
        if (val) {
#pragma unroll
            for (int i = 0; i < 4; ++i) {
                c0[i] = *(const float4*)(cptr + i * 4);
                w0[i] = *(const float4*)(wptr + i * 4);
            }
        }
        bf16x8 wr0 = *(const bf16x8*)(wgp0);
        bf16x8 wr1 = *(const bf16x8*)(wgp1);
        bf16x8 wr2 = w3 ? *(const bf16x8*)(wgp2) : (bf16x8)0;
        bf16x8 f0, f1;
        if (val) {
#pragma unroll
            for (int i = 0; i < 2; ++i) {
                f0[i * 4 + 0] = (__bf16)(w0[i].x * rate + c0[i].x * crate);
                f0[i * 4 + 1] = (__bf16)(w0[i].y * rate + c0[i].y * crate);
                f0[i * 4 + 2] = (__bf16)(w0[i].z * rate + c0[i].z * crate);
                f0[i * 4 + 3] = (__bf16)(w0[i].w * rate + c0[i].w * crate);
                f1[i * 4 + 0] = (__bf16)(w0[i + 2].x * rate + c0[i + 2].x * crate);
                f1[i * 4 + 1] = (__bf16)(w0[i + 2].y * rate + c0[i + 2].y * crate);
                f1[i * 4 + 2] = (__bf16)(w0[i + 2].z * rate + c0[i + 2].z * crate);
                f1[i * 4 + 3] = (__bf16)(w0[i + 2].w * rate + c0[i + 2].w * crate);
            }
        } else {
            f0 = (bf16x8)0; f1 = (bf16x8)0;
        }
        *(bf16x8*)(smem + awr0) = f0;
        *(bf16x8*)(smem + awr1) = f1;
        *(bf16x8*)(smem + 24576 + wwr0) = wr0;
        *(bf16x8*)(smem + 24576 + wwr1) = wr1;
        if (w3) *(bf16x8*)(smem + 24576 + wwr2) = wr2;
        // prefetch chunk 1
        if (val) {
#pragma unroll
            for (int i = 0; i < 4; ++i) {
                ac[i] = *(const float4*)(cptr + CHK + i * 4);
                aw[i] = *(const float4*)(wptr + CHK + i * 4);
            }
        }
        wreg0 = *(const bf16x8*)(wgp0 + CHK);
        wreg1 = *(const bf16x8*)(wgp1 + CHK);
        wreg2 = w3 ? *(const bf16x8*)(wgp2 + CHK) : (bf16x8)0;
    }
    __syncthreads();

    // ---- main loop ----
    for (int ch = 0; ch < NCH; ++ch) {
        // 1) commit prefetched chunk ch+1 to LDS
        if (ch + 1 < NCH) {
            char* An = smem + ((ch + 1) % 3) * 8192;
            char* Wn = smem + 24576 + ((ch + 1) & 1) * 10240;
            bf16x8 f0, f1;
            if (val) {
#pragma unroll
                for (int i = 0; i < 2; ++i) {
                    f0[i * 4 + 0] = (__bf16)(aw[i].x * rate + ac[i].x * crate);
                    f0[i * 4 + 1] = (__bf16)(aw[i].y * rate + ac[i].y * crate);
                    f0[i * 4 + 2] = (__bf16)(aw[i].z * rate + ac[i].z * crate);
                    f0[i * 4 + 3] = (__bf16)(aw[i].w * rate + ac[i].w * crate);
                    f1[i * 4 + 0] = (__bf16)(aw[i + 2].x * rate + ac[i + 2].x * crate);
                    f1[i * 4 + 1] = (__bf16)(aw[i + 2].y * rate + ac[i + 2].y * crate);
                    f1[i * 4 + 2] = (__bf16)(aw[i + 2].z * rate + ac[i + 2].z * crate);
                    f1[i * 4 + 3] = (__bf16)(aw[i + 2].w * rate + ac[i + 2].w * crate);
                }
            } else {
                f0 = (bf16x8)0; f1 = (bf16x8)0;
            }
            *(bf16x8*)(An + awr0) = f0;
            *(bf16x8*)(An + awr1) = f1;
            *(bf16x8*)(Wn + wwr0) = wreg0;
            *(bf16x8*)(Wn + wwr1) = wreg1;
            if (w3) *(bf16x8*)(Wn + wwr2) = wreg2;
        }
        // 2) issue global loads for chunk ch+2 (held in regs across compute)
        if (ch + 2 < NCH) {
            const int ko = (ch + 2) * CHK;
            if (val) {
#pragma unroll
                for (int i = 0; i < 4; ++i) {
                    ac[i] = *(const float4*)(cptr + ko + i * 4);
                    aw[i] = *(const float4*)(wptr + ko + i * 4);
                }
            }
            wreg0 = *(const bf16x8*)(wgp0 + ko);
            wreg1 = *(const bf16x8*)(wgp1 + ko);
            wreg2 = w3 ? *(const bf16x8*)(wgp2 + ko) : (bf16x8)0;
        }
        // 3) compute chunk ch
        const char* Ab = smem + (ch % 3) * 8192;
        const char* Wb = smem + 24576 + (ch & 1) * 10240;
#pragma unroll
        for (int s = 0; s < 2; ++s) {
            bf16x8 a = *(const bf16x8*)(Ab + aoff[s]);
#pragma unroll
            for (int nt = 0; nt < 5; ++nt) {
                bf16x8 bw = *(const bf16x8*)(Wb + woff[s][nt]);
                acc[nt] = __builtin_amdgcn_mfma_f32_16x16x32_bf16(a, bw, acc[nt], 0, 0, 0);
            }
        }
        __syncthreads();
    }

    // ---- epilogue: direct C write (no split-K). col = lane&15, row = (lane>>4)*4 + reg ----
    const int orow = rowbase + wv * 16 + kgrp * 4;
#pragma unroll
    for (int nt = 0; nt < 5; ++nt) {
        const int col = nt * 16 + l15;
        if (col < NTAGS) {
            const float bias = b_out[col];
#pragma unroll
            for (int i = 0; i < 4; ++i) {
                out[(size_t)(orow + i) * NTAGS + col] = acc[nt][i] + bias;
            }
        }
    }
}

extern "C" void kernel_launch(void* const* d_in, const int* in_sizes, int n_in,
                              void* d_out, int out_size, void* d_ws, size_t ws_size,
                              hipStream_t stream) {
    const float* out_char = (const float*)d_in[0];
    const float* out_word = (const float*)d_in[1];
    const int* word_idx = (const int*)d_in[2];
    const int* is_head = (const int*)d_in[3];
    const int* valid_mask = (const int*)d_in[4];
    const float* W_out = (const float*)d_in[5];
    const float* b_out = (const float*)d_in[6];
    float* out = (float*)d_out;
    __bf16* Wt = (__bf16*)d_ws;  // 80*1024*2 = 160 KB

    prep_w_kernel<<<HH / 64, 256, 0, stream>>>(W_out, Wt);

    const int rows = 16 * TT;  // B*T = 32768
    slu_main<<<rows / MROWS, 256, 0, stream>>>(out_char, out_word, word_idx, is_head,
                                               valid_mask, Wt, b_out, out);
}